// Round 4
// baseline (1998.849 us; speedup 1.0000x reference)
//
#include <hip/hip_runtime.h>
#include <hip/hip_bf16.h>

// ---------------------------------------------------------------------------
// AttentionMIL: x[16,4096,1024] -> Linear+LN+ReLU -> Linear+LN+ReLU ->
//               attention (tanh linear -> scalar -> softmax over N) ->
//               weighted pool -> 2-layer classifier -> logits [16,2]
// ---------------------------------------------------------------------------

#define MTOT   65536
#define DDIM   1024
#define HDIM   512
#define NBAG   16
#define NINST  4096

typedef __attribute__((ext_vector_type(8))) short bf16x8;
typedef __attribute__((ext_vector_type(4))) float f32x4;

__device__ __forceinline__ unsigned short f2bf(float f) {
  __hip_bfloat16 h = __float2bfloat16(f);
  unsigned short u;
  __builtin_memcpy(&u, &h, 2);
  return u;
}
__device__ __forceinline__ float bf2f(unsigned short u) {
  unsigned int x = ((unsigned int)u) << 16;
  float f;
  __builtin_memcpy(&f, &x, 4);
  return f;
}

__device__ __forceinline__ void gload16(const void* g, void* l) {
  __builtin_amdgcn_global_load_lds(
      (const __attribute__((address_space(1))) unsigned int*)g,
      (__attribute__((address_space(3))) unsigned int*)l, 16, 0, 0);
}

__device__ __forceinline__ bf16x8 pack8(float4 a, float4 b) {
  bf16x8 r;
  r[0] = (short)f2bf(a.x); r[1] = (short)f2bf(a.y);
  r[2] = (short)f2bf(a.z); r[3] = (short)f2bf(a.w);
  r[4] = (short)f2bf(b.x); r[5] = (short)f2bf(b.y);
  r[6] = (short)f2bf(b.z); r[7] = (short)f2bf(b.w);
  return r;
}

#define VMW(N) asm volatile("s_waitcnt vmcnt(" #N ")" ::: "memory")
#define LKW0   asm volatile("s_waitcnt lgkmcnt(0)" ::: "memory")

// ---------------------------------------------------------------------------
// transpose + cast f32 [R][C] -> bf16 [C][R]
// ---------------------------------------------------------------------------
__global__ void transpose_cast(const float* __restrict__ src,
                               __hip_bfloat16* __restrict__ dst,
                               int R, int C) {
  __shared__ float t[32][33];
  const int c0 = blockIdx.x * 32, r0 = blockIdx.y * 32;
  const int tx = threadIdx.x, ty = threadIdx.y;  // 32 x 8
#pragma unroll
  for (int i = 0; i < 32; i += 8)
    t[ty + i][tx] = src[(size_t)(r0 + ty + i) * C + c0 + tx];
  __syncthreads();
#pragma unroll
  for (int i = 0; i < 32; i += 8)
    dst[(size_t)(c0 + ty + i) * R + r0 + tx] = __float2bfloat16(t[tx][ty + i]);
}

// ---------------------------------------------------------------------------
// Fused GEMM: out = A[M x KD] * BT^T    (BT = W^T, [512][KD] row-major)
// MODE 0: relu(LN(y+bias, g, b)) -> bf16      MODE 1: tanh(y+bias).wa2 -> f32
// Tile 128 x 512 (full width so LN fuses), BK=32, 8 waves (2M x 4N),
// wave tile 64x128. LDS exactly 80KB (At 2x8KB + Bt 2x32KB; epilogue arrays
// alias dead At space) -> 2 blocks/CU. Chunk-remapped LDS: each 16row x 32col
// 1KB chunk written lane-linear by global_load_lds with pre-swizzled per-lane
// source (row=l&15, slot=(l>>4)^(l&3)); fragment reads are bank-perfect.
// Issue-early 1-deep prefetch: tile t+2 loads issued post-MFMA barrier of
// step t; the VMW(0) drain of tile t+1 has a full step of latency cover.
// ---------------------------------------------------------------------------
#define BM 128
#define BK 32

template <int KD, bool AF32, int MODE>
__global__ __launch_bounds__(512, 4)
void gemm_fused(const void* Ap, const __hip_bfloat16* __restrict__ BT,
                const float* __restrict__ bias, const float* __restrict__ gg,
                const float* __restrict__ bb, const float* __restrict__ wa2,
                const float* __restrict__ ba2, __hip_bfloat16* __restrict__ outh,
                float* __restrict__ outs) {
  __shared__ __align__(16) char smem[81920];
  __hip_bfloat16* At0 = (__hip_bfloat16*)smem;            // [2][4096] elems
  __hip_bfloat16* Bt0 = (__hip_bfloat16*)(smem + 16384);  // [2][16384] elems

  const int tid  = threadIdx.x;
  const int lane = tid & 63;
  const int w    = tid >> 6;
  const int wm   = w >> 2;      // 0..1
  const int wn   = w & 3;       // 0..3
  const int l16  = lane & 15;
  const int lg   = lane >> 4;   // 0..3
  const size_t row0 = (size_t)blockIdx.x * BM;

  // staging: lane l of a wave fills byte 16*l of a 1KB chunk; the data that
  // belongs there is (row = l&15, K-slot = (l>>4)^(l&3)) of the chunk.
  const int rS = lane & 15;
  const int sS = (lane >> 4) ^ (lane & 3);
  const int dOff = lane * 8;  // element offset within chunk (8 bf16 = 16B)

  // consumer: fragment (16 rows x 8 K-elems per lane-group) within a chunk
  const int frag_off = l16 * 8 + ((lg ^ (l16 & 3)) << 7);

  constexpr int NT = KD / BK;  // 32 (GEMM1) / 16 (GEMM2,3)
  const __hip_bfloat16* Abf = (const __hip_bfloat16*)Ap;
  const float* Af32 = (const float*)Ap;

  f32x4 acc[4][8];
#pragma unroll
  for (int i = 0; i < 4; i++)
#pragma unroll
    for (int j = 0; j < 8; j++) acc[i][j] = (f32x4){0.f, 0.f, 0.f, 0.f};

  auto issueB = [&](int kb, int buf) {
    __hip_bfloat16* dst = Bt0 + buf * 16384;
#pragma unroll
    for (int i = 0; i < 4; i++) {
      const int c = w * 4 + i;  // chunk = 16 B-rows
      gload16(BT + (size_t)(c * 16 + rS) * KD + kb + sS * 8,
              dst + c * 512 + dOff);
    }
  };
  auto issueA_g = [&](int kb, int buf) {
    gload16(Abf + (row0 + w * 16 + rS) * KD + kb + sS * 8,
            At0 + buf * 4096 + w * 512 + dOff);
  };

  float4 fr0a, fr0b, fr1a, fr1b;  // f32 A staging regs
#define LOADA_(FA, FB, TT)                                                     \
  { const float* gp_ = Af32 + (row0 + w * 16 + rS) * KD + (TT) * BK + sS * 8;  \
    FA = *reinterpret_cast<const float4*>(gp_);                                \
    FB = *reinterpret_cast<const float4*>(gp_ + 4); }
#define CVTA_(FA, FB, BUF)                                                     \
  *reinterpret_cast<bf16x8*>(At0 + (BUF) * 4096 + w * 512 + dOff) =            \
      pack8(FA, FB);

  // ---- prologue: tiles 0 and 1 ----
  if constexpr (AF32) {
    LOADA_(fr0a, fr0b, 0);
    issueB(0, 0);
    LOADA_(fr1a, fr1b, 1);
    issueB(BK, 1);
    VMW(0);              // one-time full drain (safe under any reorder)
    CVTA_(fr0a, fr0b, 0);
    CVTA_(fr1a, fr1b, 1);
    LKW0;
  } else {
    issueA_g(0, 0);
    issueB(0, 0);
    issueA_g(BK, 1);
    issueB(BK, 1);
    VMW(0);              // one-time full drain
  }

  // ---- main loop: 2 barriers/step, issue-early prefetch depth 1.5 steps ----
#define STEP(J, T)                                                             \
  {                                                                            \
    __builtin_amdgcn_s_barrier();                                              \
    bf16x8 af[4], bfr[8];                                                      \
    const __hip_bfloat16* Ab_ = At0 + (J) * 4096;                              \
    const __hip_bfloat16* Bb_ = Bt0 + (J) * 16384;                             \
    _Pragma("unroll") for (int fm = 0; fm < 4; fm++)                           \
      af[fm] = *reinterpret_cast<const bf16x8*>(                               \
          Ab_ + (wm * 4 + fm) * 512 + frag_off);                               \
    _Pragma("unroll") for (int fn = 0; fn < 8; fn++)                           \
      bfr[fn] = *reinterpret_cast<const bf16x8*>(                              \
          Bb_ + (wn * 8 + fn) * 512 + frag_off);                               \
    if constexpr (AF32) {                                                      \
      if ((T) + 2 < NT) { LOADA_(fr0a, fr0b, (T) + 2); }                       \
    }                                                                          \
    LKW0;                                                                      \
    __builtin_amdgcn_sched_barrier(0);                                         \
    __builtin_amdgcn_s_setprio(1);                                             \
    _Pragma("unroll") for (int fm = 0; fm < 4; fm++)                           \
      _Pragma("unroll") for (int fn = 0; fn < 8; fn++)                         \
        acc[fm][fn] = __builtin_amdgcn_mfma_f32_16x16x32_bf16(                 \
            af[fm], bfr[fn], acc[fm][fn], 0, 0, 0);                            \
    __builtin_amdgcn_s_setprio(0);                                             \
    __builtin_amdgcn_sched_barrier(0);                                         \
    __builtin_amdgcn_s_barrier();                                              \
    VMW(0);  /* drain tile t+1 gloads (>=1 step cover) + A regs (MFMA cover) */\
    if ((T) + 2 < NT) {                                                        \
      if constexpr (AF32) { CVTA_(fr0a, fr0b, (J)); }                          \
      else { issueA_g(((T) + 2) * BK, (J)); }                                  \
      issueB(((T) + 2) * BK, (J));                                             \
      if constexpr (AF32) { LKW0; }                                            \
    }                                                                          \
  }

  for (int tb = 0; tb < NT; tb += 2) {
    STEP(0, tb)
    STEP(1, tb + 1)
  }
#undef STEP
#undef LOADA_
#undef CVTA_

  // ---------------- epilogue (reduction arrays alias dead At space) --------
  float (*redS)[4] = (float(*)[4])smem;            // 2 KB
  float (*redQ)[4] = (float(*)[4])(smem + 2048);   // 2 KB
  float* muL = (float*)(smem + 4096);              // 0.5 KB
  float* rsL = (float*)(smem + 4608);              // 0.5 KB

  float biasv[8];
#pragma unroll
  for (int fn = 0; fn < 8; fn++) biasv[fn] = bias[wn * 128 + fn * 16 + l16];

  if (MODE == 0) {
    float gv[8], bv[8];
#pragma unroll
    for (int fn = 0; fn < 8; fn++) {
      const int col = wn * 128 + fn * 16 + l16;
      gv[fn] = gg[col];
      bv[fn] = bb[col];
    }
#pragma unroll
    for (int fm = 0; fm < 4; fm++)
#pragma unroll
      for (int r = 0; r < 4; r++) {
        float s1 = 0.f, s2 = 0.f;
#pragma unroll
        for (int fn = 0; fn < 8; fn++) {
          const float v = acc[fm][fn][r] + biasv[fn];
          s1 += v;
          s2 += v * v;
        }
#pragma unroll
        for (int m = 1; m < 16; m <<= 1) {
          s1 += __shfl_xor(s1, m);
          s2 += __shfl_xor(s2, m);
        }
        if (l16 == 0) {
          const int rl = wm * 64 + fm * 16 + lg * 4 + r;
          redS[rl][wn] = s1;
          redQ[rl][wn] = s2;
        }
      }
    __syncthreads();
    if (tid < BM) {
      const float S = redS[tid][0] + redS[tid][1] + redS[tid][2] + redS[tid][3];
      const float Q = redQ[tid][0] + redQ[tid][1] + redQ[tid][2] + redQ[tid][3];
      const float mean = S * (1.f / 512.f);
      const float var = Q * (1.f / 512.f) - mean * mean;
      muL[tid] = mean;
      rsL[tid] = rsqrtf(var + 1e-5f);
    }
    __syncthreads();
#pragma unroll
    for (int fm = 0; fm < 4; fm++)
#pragma unroll
      for (int r = 0; r < 4; r++) {
        const int rl = wm * 64 + fm * 16 + lg * 4 + r;
        const float mu = muL[rl], rs = rsL[rl];
#pragma unroll
        for (int fn = 0; fn < 8; fn++) {
          const float v = acc[fm][fn][r] + biasv[fn];
          float y = (v - mu) * rs * gv[fn] + bv[fn];
          y = fmaxf(y, 0.f);
          outh[(row0 + rl) * HDIM + wn * 128 + fn * 16 + l16] =
              __float2bfloat16(y);
        }
      }
  } else {
    float wv[8];
#pragma unroll
    for (int fn = 0; fn < 8; fn++) wv[fn] = wa2[wn * 128 + fn * 16 + l16];
#pragma unroll
    for (int fm = 0; fm < 4; fm++)
#pragma unroll
      for (int r = 0; r < 4; r++) {
        float s = 0.f;
#pragma unroll
        for (int fn = 0; fn < 8; fn++) {
          const float v = acc[fm][fn][r] + biasv[fn];
          s += tanhf(v) * wv[fn];
        }
#pragma unroll
        for (int m = 1; m < 16; m <<= 1) s += __shfl_xor(s, m);
        if (l16 == 0) redS[wm * 64 + fm * 16 + lg * 4 + r][wn] = s;
      }
    __syncthreads();
    if (tid < BM) {
      outs[row0 + tid] =
          redS[tid][0] + redS[tid][1] + redS[tid][2] + redS[tid][3] + ba2[0];
    }
  }
}

// ---------------------------------------------------------------------------
// softmax over 4096 instances per bag
// ---------------------------------------------------------------------------
__global__ void softmax_bag(const float* __restrict__ sc, float* __restrict__ at) {
  const int b = blockIdx.x;
  const int tid = threadIdx.x;  // 256
  const int lane = tid & 63, w = tid >> 6;
  const float* s = sc + (size_t)b * NINST;
  float v[16];
  float mx = -1e30f;
#pragma unroll
  for (int i = 0; i < 16; i++) {
    v[i] = s[tid + i * 256];
    mx = fmaxf(mx, v[i]);
  }
#pragma unroll
  for (int off = 32; off; off >>= 1) mx = fmaxf(mx, __shfl_xor(mx, off));
  __shared__ float red[4];
  if (lane == 0) red[w] = mx;
  __syncthreads();
  mx = fmaxf(fmaxf(red[0], red[1]), fmaxf(red[2], red[3]));
  float sum = 0.f;
#pragma unroll
  for (int i = 0; i < 16; i++) {
    v[i] = expf(v[i] - mx);
    sum += v[i];
  }
#pragma unroll
  for (int off = 32; off; off >>= 1) sum += __shfl_xor(sum, off);
  __shared__ float red2[4];
  if (lane == 0) red2[w] = sum;
  __syncthreads();
  sum = red2[0] + red2[1] + red2[2] + red2[3];
  const float inv = 1.f / sum;
#pragma unroll
  for (int i = 0; i < 16; i++) at[(size_t)b * NINST + tid + i * 256] = v[i] * inv;
}

// ---------------------------------------------------------------------------
// pooled[b,h] = sum_n attn[b,n] * h2[b,n,h]
// ---------------------------------------------------------------------------
__global__ void pooled_partial(const __hip_bfloat16* __restrict__ h2,
                               const float* __restrict__ at,
                               float* __restrict__ part) {
  const int bid = blockIdx.x;
  const int b = bid >> 5, cc = (bid >> 3) & 3, nch = bid & 7;
  const int tid = threadIdx.x;  // 256
  const int c4 = (tid & 31) * 4, sub = tid >> 5;
  const int n0 = nch * 512;
  const size_t base = (size_t)b * NINST;
  float a0 = 0.f, a1 = 0.f, a2 = 0.f, a3 = 0.f;
  for (int n = n0 + sub; n < n0 + 512; n += 8) {
    const float a = at[base + n];
    const ushort4 u = *reinterpret_cast<const ushort4*>(
        &h2[(base + n) * HDIM + cc * 128 + c4]);
    a0 += a * bf2f(u.x);
    a1 += a * bf2f(u.y);
    a2 += a * bf2f(u.z);
    a3 += a * bf2f(u.w);
  }
  __shared__ float pb[8][128];
  pb[sub][c4 + 0] = a0;
  pb[sub][c4 + 1] = a1;
  pb[sub][c4 + 2] = a2;
  pb[sub][c4 + 3] = a3;
  __syncthreads();
  if (tid < 128) {
    float s = 0.f;
#pragma unroll
    for (int j = 0; j < 8; j++) s += pb[j][tid];
    part[(size_t)nch * 8192 + b * 512 + cc * 128 + tid] = s;
  }
}

__global__ void pooled_reduce(const float* __restrict__ part,
                              float* __restrict__ pooled) {
  const int i = blockIdx.x * 256 + threadIdx.x;  // 8192 total
  float s = 0.f;
#pragma unroll
  for (int j = 0; j < 8; j++) s += part[(size_t)j * 8192 + i];
  pooled[i] = s;
}

// ---------------------------------------------------------------------------
// classifier
// ---------------------------------------------------------------------------
__global__ void classifier(const float* __restrict__ pooled,
                           const float* __restrict__ Wc1,
                           const float* __restrict__ bc1,
                           const float* __restrict__ Wc2,
                           const float* __restrict__ bc2,
                           float* __restrict__ out) {
  __shared__ float P[NBAG][512];
  __shared__ float Rb[NBAG][512];
  const int tid = threadIdx.x;  // 512
#pragma unroll
  for (int i = 0; i < NBAG; i++) P[i][tid] = pooled[i * 512 + tid];
  __syncthreads();
  float r[NBAG];
#pragma unroll
  for (int i = 0; i < NBAG; i++) r[i] = 0.f;
  for (int k = 0; k < 512; k++) {
    const float wv = Wc1[k * 512 + tid];
#pragma unroll
    for (int i = 0; i < NBAG; i++) r[i] += P[i][k] * wv;
  }
#pragma unroll
  for (int i = 0; i < NBAG; i++) Rb[i][tid] = fmaxf(r[i] + bc1[tid], 0.f);
  __syncthreads();
  if (tid < 32) {
    const int i = tid >> 1, c = tid & 1;
    float s = bc2[c];
    for (int k = 0; k < 512; k++) s += Rb[i][k] * Wc2[k * 2 + c];
    out[i * 2 + c] = s;
  }
}

// ---------------------------------------------------------------------------
extern "C" void kernel_launch(void* const* d_in, const int* in_sizes, int n_in,
                              void* d_out, int out_size, void* d_ws,
                              size_t ws_size, hipStream_t stream) {
  const float* x   = (const float*)d_in[0];
  const float* W1  = (const float*)d_in[1];
  const float* b1  = (const float*)d_in[2];
  const float* g1  = (const float*)d_in[3];
  const float* be1 = (const float*)d_in[4];
  const float* W2  = (const float*)d_in[5];
  const float* b2  = (const float*)d_in[6];
  const float* g2  = (const float*)d_in[7];
  const float* be2 = (const float*)d_in[8];
  const float* Wa1 = (const float*)d_in[9];
  const float* ba1 = (const float*)d_in[10];
  const float* wa2 = (const float*)d_in[11];
  const float* ba2 = (const float*)d_in[12];
  const float* Wc1 = (const float*)d_in[13];
  const float* bc1 = (const float*)d_in[14];
  const float* Wc2 = (const float*)d_in[15];
  const float* bc2 = (const float*)d_in[16];
  float* out = (float*)d_out;

  char* ws = (char*)d_ws;
  __hip_bfloat16* W1T = (__hip_bfloat16*)(ws + 0);          // 1 MB
  __hip_bfloat16* W2T = (__hip_bfloat16*)(ws + 1048576);    // 512 KB
  __hip_bfloat16* WaT = (__hip_bfloat16*)(ws + 1572864);    // 512 KB
  float* scores = (float*)(ws + 2097152);                   // 256 KB
  float* attn   = (float*)(ws + 2359296);                   // 256 KB
  float* part   = (float*)(ws + 2621440);                   // 256 KB
  float* pooled = (float*)(ws + 2883584);                   // 32 KB
  __hip_bfloat16* hbuf = (__hip_bfloat16*)(ws + 4194304);   // 64 MB

  transpose_cast<<<dim3(16, 32), dim3(32, 8), 0, stream>>>(W1, W1T, DDIM, HDIM);
  transpose_cast<<<dim3(16, 16), dim3(32, 8), 0, stream>>>(W2, W2T, HDIM, HDIM);
  transpose_cast<<<dim3(16, 16), dim3(32, 8), 0, stream>>>(Wa1, WaT, HDIM, HDIM);

  gemm_fused<DDIM, true, 0><<<MTOT / BM, 512, 0, stream>>>(
      x, W1T, b1, g1, be1, nullptr, nullptr, hbuf, nullptr);
  gemm_fused<HDIM, false, 0><<<MTOT / BM, 512, 0, stream>>>(
      hbuf, W2T, b2, g2, be2, nullptr, nullptr, hbuf, nullptr);
  gemm_fused<HDIM, false, 1><<<MTOT / BM, 512, 0, stream>>>(
      hbuf, WaT, ba1, nullptr, nullptr, wa2, ba2, nullptr, scores);

  softmax_bag<<<NBAG, 256, 0, stream>>>(scores, attn);
  pooled_partial<<<512, 256, 0, stream>>>(hbuf, attn, part);
  pooled_reduce<<<32, 256, 0, stream>>>(part, pooled);
  classifier<<<1, 512, 0, stream>>>(pooled, Wc1, bc1, Wc2, bc2, out);
}

// Round 5
// 459.959 us; speedup vs baseline: 4.3457x; 4.3457x over previous
//
#include <hip/hip_runtime.h>
#include <hip/hip_bf16.h>

// ---------------------------------------------------------------------------
// AttentionMIL: x[16,4096,1024] -> Linear+LN+ReLU -> Linear+LN+ReLU ->
//               attention (tanh linear -> scalar -> softmax over N) ->
//               weighted pool -> 2-layer classifier -> logits [16,2]
//
// Architecture (round 5): de-fused LN. GEMMs use the proven m97 geometry
// (128x128 tile, BK=32, 4 waves, 16KB single-buffer LDS, gload_lds w=16,
// ~3 blocks/CU). Each GEMM block emits y-tile bf16 + per-row partial
// (sum, sumsq) f32; ln_apply combines 4 partials/row and applies
// relu(LN) in-place. GEMM3 emits partial tanh-scores; softmax combines.
// ---------------------------------------------------------------------------

#define MTOT   65536
#define DDIM   1024
#define HDIM   512
#define NBAG   16
#define NINST  4096

typedef __attribute__((ext_vector_type(8))) short bf16x8;
typedef __attribute__((ext_vector_type(4))) float f32x4;

__device__ __forceinline__ unsigned short f2bf(float f) {
  __hip_bfloat16 h = __float2bfloat16(f);
  unsigned short u;
  __builtin_memcpy(&u, &h, 2);
  return u;
}
__device__ __forceinline__ float bf2f(unsigned short u) {
  unsigned int x = ((unsigned int)u) << 16;
  float f;
  __builtin_memcpy(&f, &x, 4);
  return f;
}

__device__ __forceinline__ void gload16(const void* g, void* l) {
  __builtin_amdgcn_global_load_lds(
      (const __attribute__((address_space(1))) unsigned int*)g,
      (__attribute__((address_space(3))) unsigned int*)l, 16, 0, 0);
}

__device__ __forceinline__ bf16x8 pack8(float4 a, float4 b) {
  bf16x8 r;
  r[0] = (short)f2bf(a.x); r[1] = (short)f2bf(a.y);
  r[2] = (short)f2bf(a.z); r[3] = (short)f2bf(a.w);
  r[4] = (short)f2bf(b.x); r[5] = (short)f2bf(b.y);
  r[6] = (short)f2bf(b.z); r[7] = (short)f2bf(b.w);
  return r;
}

// ---------------------------------------------------------------------------
// transpose + cast f32 [R][C] -> bf16 [C][R]
// ---------------------------------------------------------------------------
__global__ void transpose_cast(const float* __restrict__ src,
                               __hip_bfloat16* __restrict__ dst,
                               int R, int C) {
  __shared__ float t[32][33];
  const int c0 = blockIdx.x * 32, r0 = blockIdx.y * 32;
  const int tx = threadIdx.x, ty = threadIdx.y;  // 32 x 8
#pragma unroll
  for (int i = 0; i < 32; i += 8)
    t[ty + i][tx] = src[(size_t)(r0 + ty + i) * C + c0 + tx];
  __syncthreads();
#pragma unroll
  for (int i = 0; i < 32; i += 8)
    dst[(size_t)(c0 + ty + i) * R + r0 + tx] = __float2bfloat16(t[tx][ty + i]);
}

// ---------------------------------------------------------------------------
// GEMM tile kernel (m97 geometry): C-tile = A[128 x KD] * BT[128 rows of W^T]
// MODE 0: write y=z (bf16) + per-row partial (sum z, sum z^2) -> statp[row][4]
// MODE 1: write per-row partial sum tanh(z)*wa2 -> scorep[row][4]
// 256 threads, 4 waves (2M x 2N), wave tile 64x64 (fm=4, fn=4, acc 64 VGPR).
// LDS 16KB single-buffered, chunk-swizzled (1KB chunk = 16 rows x 32 cols;
// lane l holds (row=l&15, kslot=(l>>4)^(l&3)) at byte 16*l -> gload_lds-legal
// linear dest, pre-swizzled per-lane global source; fragment reads bank-clean
// (measured 0 conflicts round 4).
// ---------------------------------------------------------------------------
#define BM 128
#define BN 128
#define BK 32

template <int KD, bool AF32, int MODE>
__global__ __launch_bounds__(256, AF32 ? 2 : 3)
void gemm_tile(const void* Ap, const __hip_bfloat16* __restrict__ BT,
               const float* __restrict__ bias,
               __hip_bfloat16* __restrict__ ybuf,
               float2* __restrict__ statp,
               const float* __restrict__ wa2,
               float* __restrict__ scorep) {
  __shared__ __align__(16) char smem[16384];
  __hip_bfloat16* AtP = (__hip_bfloat16*)smem;            // 8 KB (8 chunks)
  __hip_bfloat16* BtP = (__hip_bfloat16*)(smem + 8192);   // 8 KB

  const int tid  = threadIdx.x;     // 256
  const int lane = tid & 63;
  const int w    = tid >> 6;        // 4 waves
  const int wm   = w >> 1;          // 0..1
  const int wn   = w & 1;           // 0..1
  const int l16  = lane & 15;
  const int lg   = lane >> 4;       // 0..3

  // XCD-bijective remap (grid 2048 % 8 == 0): siblings (4 n-blocks of a row
  // panel) stay adjacent -> same XCD L2 for the shared A panel.
  const int cpx = gridDim.x >> 3;
  int bid = blockIdx.x;
  bid = (bid & 7) * cpx + (bid >> 3);
  const int n_blk   = bid & 3;          // 512 / BN
  const int row_blk = bid >> 2;
  const size_t row0 = (size_t)row_blk * BM;
  const int col0    = n_blk * BN;

  // staging geometry
  const int rS   = lane & 15;                 // row within chunk
  const int sS   = (lane >> 4) ^ (lane & 3);  // source k-slot (pre-swizzle)
  const int dOff = lane * 8;                  // dest elems within chunk
  // consumer fragment offset within a chunk
  const int frag_off = l16 * 8 + ((lg ^ (l16 & 3)) << 7);

  constexpr int NT = KD / BK;  // 32 (GEMM1) / 16 (GEMM2,3)
  const __hip_bfloat16* Abf = (const __hip_bfloat16*)Ap;
  const float* Af32 = (const float*)Ap;

  f32x4 acc[4][4];
#pragma unroll
  for (int i = 0; i < 4; i++)
#pragma unroll
    for (int j = 0; j < 4; j++) acc[i][j] = (f32x4){0.f, 0.f, 0.f, 0.f};

  auto stageB = [&](int kb) {
#pragma unroll
    for (int i = 0; i < 2; i++) {
      const int c = w * 2 + i;  // chunk 0..7 = 16 BT-rows (output cols)
      gload16(BT + (size_t)(col0 + c * 16 + rS) * KD + kb + sS * 8,
              BtP + c * 512 + dOff);
    }
  };
  auto stageA_g = [&](int kb) {
#pragma unroll
    for (int i = 0; i < 2; i++) {
      const int c = w * 2 + i;
      gload16(Abf + (row0 + c * 16 + rS) * KD + kb + sS * 8,
              AtP + c * 512 + dOff);
    }
  };

  float4 f0_0a, f0_0b, f0_1a, f0_1b, f1_0a, f1_0b, f1_1a, f1_1b;
#define LOADA_(S, KB)                                                          \
  { const float* g0_ = Af32 + (row0 + (w * 2 + 0) * 16 + rS) * KD + (KB) + sS * 8; \
    const float* g1_ = Af32 + (row0 + (w * 2 + 1) * 16 + rS) * KD + (KB) + sS * 8; \
    f##S##_0a = *(const float4*)g0_; f##S##_0b = *(const float4*)(g0_ + 4);    \
    f##S##_1a = *(const float4*)g1_; f##S##_1b = *(const float4*)(g1_ + 4); }
#define WRITEA_(S)                                                             \
  { *reinterpret_cast<bf16x8*>(AtP + (w * 2 + 0) * 512 + dOff) =               \
        pack8(f##S##_0a, f##S##_0b);                                           \
    *reinterpret_cast<bf16x8*>(AtP + (w * 2 + 1) * 512 + dOff) =               \
        pack8(f##S##_1a, f##S##_1b); }

#define FRAGS_DECL                                                             \
  bf16x8 af[4], bfr[4];                                                        \
  _Pragma("unroll") for (int fm = 0; fm < 4; fm++)                             \
      af[fm] = *reinterpret_cast<const bf16x8*>(                               \
          AtP + (wm * 4 + fm) * 512 + frag_off);                               \
  _Pragma("unroll") for (int fn = 0; fn < 4; fn++)                             \
      bfr[fn] = *reinterpret_cast<const bf16x8*>(                              \
          BtP + (wn * 4 + fn) * 512 + frag_off);

#define MFMAS                                                                  \
  _Pragma("unroll") for (int fm = 0; fm < 4; fm++)                             \
  _Pragma("unroll") for (int fn = 0; fn < 4; fn++)                             \
      acc[fm][fn] = __builtin_amdgcn_mfma_f32_16x16x32_bf16(                   \
          af[fm], bfr[fn], acc[fm][fn], 0, 0, 0);

  if constexpr (AF32) {
    LOADA_(0, 0);
    for (int tb = 0; tb < NT; tb += 2) {
      {  // T = tb (even), uses reg set 0, loads set 1
        WRITEA_(0);
        stageB(tb * BK);
        __syncthreads();
        FRAGS_DECL
        if (tb + 1 < NT) { LOADA_(1, (tb + 1) * BK); }
        MFMAS
        __syncthreads();
      }
      {  // T = tb+1 (odd), uses reg set 1, loads set 0
        WRITEA_(1);
        stageB((tb + 1) * BK);
        __syncthreads();
        FRAGS_DECL
        if (tb + 2 < NT) { LOADA_(0, (tb + 2) * BK); }
        MFMAS
        __syncthreads();
      }
    }
  } else {
    for (int t = 0; t < NT; ++t) {
      stageA_g(t * BK);
      stageB(t * BK);
      __syncthreads();
      FRAGS_DECL
      MFMAS
      __syncthreads();
    }
  }
#undef LOADA_
#undef WRITEA_
#undef FRAGS_DECL
#undef MFMAS

  // ---------------- epilogue: partial stats / partial scores ----------------
  float* redS = (float*)smem;          // [128][2]
  float* redQ = (float*)smem + 256;    // [128][2]

  float biasv[4];
#pragma unroll
  for (int fn = 0; fn < 4; fn++)
    biasv[fn] = bias[col0 + wn * 64 + fn * 16 + l16];

  if (MODE == 0) {
#pragma unroll
    for (int fm = 0; fm < 4; fm++)
#pragma unroll
      for (int r = 0; r < 4; r++) {
        const int rl = wm * 64 + fm * 16 + lg * 4 + r;
        float s1 = 0.f, s2 = 0.f;
#pragma unroll
        for (int fn = 0; fn < 4; fn++) {
          const float z = acc[fm][fn][r] + biasv[fn];
          s1 += z;
          s2 += z * z;
          ybuf[(row0 + rl) * HDIM + col0 + wn * 64 + fn * 16 + l16] =
              __float2bfloat16(z);
        }
#pragma unroll
        for (int m = 1; m < 16; m <<= 1) {
          s1 += __shfl_xor(s1, m);
          s2 += __shfl_xor(s2, m);
        }
        if (l16 == 0) {
          redS[rl * 2 + wn] = s1;
          redQ[rl * 2 + wn] = s2;
        }
      }
    __syncthreads();
    if (tid < BM) {
      statp[(row0 + tid) * 4 + n_blk] =
          make_float2(redS[tid * 2] + redS[tid * 2 + 1],
                      redQ[tid * 2] + redQ[tid * 2 + 1]);
    }
  } else {
    float wv[4];
#pragma unroll
    for (int fn = 0; fn < 4; fn++)
      wv[fn] = wa2[col0 + wn * 64 + fn * 16 + l16];
#pragma unroll
    for (int fm = 0; fm < 4; fm++)
#pragma unroll
      for (int r = 0; r < 4; r++) {
        const int rl = wm * 64 + fm * 16 + lg * 4 + r;
        float s = 0.f;
#pragma unroll
        for (int fn = 0; fn < 4; fn++) {
          const float z = acc[fm][fn][r] + biasv[fn];
          s += tanhf(z) * wv[fn];
        }
#pragma unroll
        for (int m = 1; m < 16; m <<= 1) s += __shfl_xor(s, m);
        if (l16 == 0) redS[rl * 2 + wn] = s;
      }
    __syncthreads();
    if (tid < BM) {
      scorep[(row0 + tid) * 4 + n_blk] = redS[tid * 2] + redS[tid * 2 + 1];
    }
  }
}

// ---------------------------------------------------------------------------
// ln_apply: h[r][c] = relu((y[r][c] - mu_r) * rs_r * g[c] + be[c]), in-place.
// Stats from 4 f32 partials per row. 64 threads/row, 4 rows/block.
// ---------------------------------------------------------------------------
__global__ __launch_bounds__(256)
void ln_apply(__hip_bfloat16* __restrict__ y,
              const float2* __restrict__ statp,
              const float* __restrict__ g, const float* __restrict__ be) {
  const int row = blockIdx.x * 4 + (threadIdx.x >> 6);
  const int c0 = (threadIdx.x & 63) * 8;
  const float2* sp = statp + (size_t)row * 4;
  float S = 0.f, Q = 0.f;
#pragma unroll
  for (int j = 0; j < 4; j++) {
    const float2 p = sp[j];
    S += p.x;
    Q += p.y;
  }
  const float mu = S * (1.f / 512.f);
  const float var = Q * (1.f / 512.f) - mu * mu;
  const float rs = rsqrtf(var + 1e-5f);

  __hip_bfloat16* yp = y + (size_t)row * HDIM + c0;
  bf16x8 v = *reinterpret_cast<const bf16x8*>(yp);
  const float4 ga = *(const float4*)(g + c0), gb = *(const float4*)(g + c0 + 4);
  const float4 ba = *(const float4*)(be + c0), bb = *(const float4*)(be + c0 + 4);
  float gv[8] = {ga.x, ga.y, ga.z, ga.w, gb.x, gb.y, gb.z, gb.w};
  float bv[8] = {ba.x, ba.y, ba.z, ba.w, bb.x, bb.y, bb.z, bb.w};
  bf16x8 o;
#pragma unroll
  for (int j = 0; j < 8; j++) {
    const float f = bf2f((unsigned short)v[j]);
    const float h = fmaxf((f - mu) * rs * gv[j] + bv[j], 0.f);
    o[j] = (short)f2bf(h);
  }
  *reinterpret_cast<bf16x8*>(yp) = o;
}

// ---------------------------------------------------------------------------
// softmax over 4096 instances per bag; input = 4 partial scores per row + ba2
// ---------------------------------------------------------------------------
__global__ void softmax_bag(const float* __restrict__ scorep,
                            const float* __restrict__ ba2,
                            float* __restrict__ at) {
  const int b = blockIdx.x;
  const int tid = threadIdx.x;  // 256
  const int lane = tid & 63, w = tid >> 6;
  const float bv = ba2[0];
  float v[16];
  float mx = -1e30f;
#pragma unroll
  for (int i = 0; i < 16; i++) {
    const float4 sp = *reinterpret_cast<const float4*>(
        scorep + ((size_t)b * NINST + tid + i * 256) * 4);
    v[i] = sp.x + sp.y + sp.z + sp.w + bv;
    mx = fmaxf(mx, v[i]);
  }
#pragma unroll
  for (int off = 32; off; off >>= 1) mx = fmaxf(mx, __shfl_xor(mx, off));
  __shared__ float red[4];
  if (lane == 0) red[w] = mx;
  __syncthreads();
  mx = fmaxf(fmaxf(red[0], red[1]), fmaxf(red[2], red[3]));
  float sum = 0.f;
#pragma unroll
  for (int i = 0; i < 16; i++) {
    v[i] = expf(v[i] - mx);
    sum += v[i];
  }
#pragma unroll
  for (int off = 32; off; off >>= 1) sum += __shfl_xor(sum, off);
  __shared__ float red2[4];
  if (lane == 0) red2[w] = sum;
  __syncthreads();
  sum = red2[0] + red2[1] + red2[2] + red2[3];
  const float inv = 1.f / sum;
#pragma unroll
  for (int i = 0; i < 16; i++) at[(size_t)b * NINST + tid + i * 256] = v[i] * inv;
}

// ---------------------------------------------------------------------------
// pooled[b,h] = sum_n attn[b,n] * h2[b,n,h]
// ---------------------------------------------------------------------------
__global__ void pooled_partial(const __hip_bfloat16* __restrict__ h2,
                               const float* __restrict__ at,
                               float* __restrict__ part) {
  const int bid = blockIdx.x;
  const int b = bid >> 5, cc = (bid >> 3) & 3, nch = bid & 7;
  const int tid = threadIdx.x;  // 256
  const int c4 = (tid & 31) * 4, sub = tid >> 5;
  const int n0 = nch * 512;
  const size_t base = (size_t)b * NINST;
  float a0 = 0.f, a1 = 0.f, a2 = 0.f, a3 = 0.f;
  for (int n = n0 + sub; n < n0 + 512; n += 8) {
    const float a = at[base + n];
    const ushort4 u = *reinterpret_cast<const ushort4*>(
        &h2[(base + n) * HDIM + cc * 128 + c4]);
    a0 += a * bf2f(u.x);
    a1 += a * bf2f(u.y);
    a2 += a * bf2f(u.z);
    a3 += a * bf2f(u.w);
  }
  __shared__ float pb[8][128];
  pb[sub][c4 + 0] = a0;
  pb[sub][c4 + 1] = a1;
  pb[sub][c4 + 2] = a2;
  pb[sub][c4 + 3] = a3;
  __syncthreads();
  if (tid < 128) {
    float s = 0.f;
#pragma unroll
    for (int j = 0; j < 8; j++) s += pb[j][tid];
    part[(size_t)nch * 8192 + b * 512 + cc * 128 + tid] = s;
  }
}

__global__ void pooled_reduce(const float* __restrict__ part,
                              float* __restrict__ pooled) {
  const int i = blockIdx.x * 256 + threadIdx.x;  // 8192 total
  float s = 0.f;
#pragma unroll
  for (int j = 0; j < 8; j++) s += part[(size_t)j * 8192 + i];
  pooled[i] = s;
}

// ---------------------------------------------------------------------------
// classifier
// ---------------------------------------------------------------------------
__global__ void classifier(const float* __restrict__ pooled,
                           const float* __restrict__ Wc1,
                           const float* __restrict__ bc1,
                           const float* __restrict__ Wc2,
                           const float* __restrict__ bc2,
                           float* __restrict__ out) {
  __shared__ float P[NBAG][512];
  __shared__ float Rb[NBAG][512];
  const int tid = threadIdx.x;  // 512
#pragma unroll
  for (int i = 0; i < NBAG; i++) P[i][tid] = pooled[i * 512 + tid];
  __syncthreads();
  float r[NBAG];
#pragma unroll
  for (int i = 0; i < NBAG; i++) r[i] = 0.f;
  for (int k = 0; k < 512; k++) {
    const float wv = Wc1[k * 512 + tid];
#pragma unroll
    for (int i = 0; i < NBAG; i++) r[i] += P[i][k] * wv;
  }
#pragma unroll
  for (int i = 0; i < NBAG; i++) Rb[i][tid] = fmaxf(r[i] + bc1[tid], 0.f);
  __syncthreads();
  if (tid < 32) {
    const int i = tid >> 1, c = tid & 1;
    float s = bc2[c];
    for (int k = 0; k < 512; k++) s += Rb[i][k] * Wc2[k * 2 + c];
    out[i * 2 + c] = s;
  }
}

// ---------------------------------------------------------------------------
extern "C" void kernel_launch(void* const* d_in, const int* in_sizes, int n_in,
                              void* d_out, int out_size, void* d_ws,
                              size_t ws_size, hipStream_t stream) {
  const float* x   = (const float*)d_in[0];
  const float* W1  = (const float*)d_in[1];
  const float* b1  = (const float*)d_in[2];
  const float* g1  = (const float*)d_in[3];
  const float* be1 = (const float*)d_in[4];
  const float* W2  = (const float*)d_in[5];
  const float* b2  = (const float*)d_in[6];
  const float* g2  = (const float*)d_in[7];
  const float* be2 = (const float*)d_in[8];
  const float* Wa1 = (const float*)d_in[9];
  const float* ba1 = (const float*)d_in[10];
  const float* wa2 = (const float*)d_in[11];
  const float* ba2 = (const float*)d_in[12];
  const float* Wc1 = (const float*)d_in[13];
  const float* bc1 = (const float*)d_in[14];
  const float* Wc2 = (const float*)d_in[15];
  const float* bc2 = (const float*)d_in[16];
  float* out = (float*)d_out;

  char* ws = (char*)d_ws;
  __hip_bfloat16* W1T = (__hip_bfloat16*)(ws + 0);          // 1 MB
  __hip_bfloat16* W2T = (__hip_bfloat16*)(ws + 1048576);    // 512 KB
  __hip_bfloat16* WaT = (__hip_bfloat16*)(ws + 1572864);    // 512 KB
  float2* statp  = (float2*)(ws + 2097152);                 // 2 MB
  float* scorep  = (float*)(ws + 4194304);                  // 1 MB
  float* attn    = (float*)(ws + 5242880);                  // 256 KB
  float* part    = (float*)(ws + 5505024);                  // 256 KB
  float* pooled  = (float*)(ws + 5767168);                  // 32 KB
  __hip_bfloat16* buf1 = (__hip_bfloat16*)(ws + 8388608);   // 64 MB (y1/h1)
  __hip_bfloat16* buf2 = (__hip_bfloat16*)(ws + 75497472);  // 64 MB (y2/h2)

  transpose_cast<<<dim3(16, 32), dim3(32, 8), 0, stream>>>(W1, W1T, DDIM, HDIM);
  transpose_cast<<<dim3(16, 16), dim3(32, 8), 0, stream>>>(W2, W2T, HDIM, HDIM);
  transpose_cast<<<dim3(16, 16), dim3(32, 8), 0, stream>>>(Wa1, WaT, HDIM, HDIM);

  const int grid = (MTOT / BM) * (HDIM / BN);  // 512 * 4 = 2048

  // GEMM1: y1 = x @ W1 + b1 (bf16) + stats
  gemm_tile<DDIM, true, 0><<<grid, 256, 0, stream>>>(
      x, W1T, b1, buf1, statp, nullptr, nullptr);
  ln_apply<<<MTOT / 4, 256, 0, stream>>>(buf1, statp, g1, be1);

  // GEMM2: y2 = h1 @ W2 + b2 (bf16) + stats
  gemm_tile<HDIM, false, 0><<<grid, 256, 0, stream>>>(
      buf1, W2T, b2, buf2, statp, nullptr, nullptr);
  ln_apply<<<MTOT / 4, 256, 0, stream>>>(buf2, statp, g2, be2);

  // GEMM3: partial scores = sum tanh(h2 @ Wa1 + ba1) * wa2
  gemm_tile<HDIM, false, 1><<<grid, 256, 0, stream>>>(
      buf2, WaT, ba1, nullptr, nullptr, wa2, scorep);

  softmax_bag<<<NBAG, 256, 0, stream>>>(scorep, ba2, attn);
  pooled_partial<<<512, 256, 0, stream>>>(buf2, attn, part);
  pooled_reduce<<<32, 256, 0, stream>>>(part, pooled);
  classifier<<<1, 512, 0, stream>>>(pooled, Wc1, bc1, Wc2, bc2, out);
}

// Round 6
// 447.271 us; speedup vs baseline: 4.4690x; 1.0284x over previous
//
#include <hip/hip_runtime.h>
#include <hip/hip_bf16.h>

// ---------------------------------------------------------------------------
// AttentionMIL: x[16,4096,1024] -> Linear+LN+ReLU -> Linear+LN+ReLU ->
//               attention (tanh linear -> scalar -> softmax over N) ->
//               weighted pool -> 2-layer classifier -> logits [16,2]
//
// Round 6: m97-exact GEMM geometry. 128x128 tile, BK=64 (32 MFMA/wave/step),
// 4 waves, 32KB single-buffered LDS, gload_lds w=16, chunk-swizzled LDS
// (0 conflicts, round-5 measured). De-fused LN via per-block partial stats.
// ---------------------------------------------------------------------------

#define MTOT   65536
#define DDIM   1024
#define HDIM   512
#define NBAG   16
#define NINST  4096

typedef __attribute__((ext_vector_type(8))) short bf16x8;
typedef __attribute__((ext_vector_type(4))) float f32x4;

__device__ __forceinline__ unsigned short f2bf(float f) {
  __hip_bfloat16 h = __float2bfloat16(f);
  unsigned short u;
  __builtin_memcpy(&u, &h, 2);
  return u;
}
__device__ __forceinline__ float bf2f(unsigned short u) {
  unsigned int x = ((unsigned int)u) << 16;
  float f;
  __builtin_memcpy(&f, &x, 4);
  return f;
}

__device__ __forceinline__ void gload16(const void* g, void* l) {
  __builtin_amdgcn_global_load_lds(
      (const __attribute__((address_space(1))) unsigned int*)g,
      (__attribute__((address_space(3))) unsigned int*)l, 16, 0, 0);
}

__device__ __forceinline__ bf16x8 pack8(float4 a, float4 b) {
  bf16x8 r;
  r[0] = (short)f2bf(a.x); r[1] = (short)f2bf(a.y);
  r[2] = (short)f2bf(a.z); r[3] = (short)f2bf(a.w);
  r[4] = (short)f2bf(b.x); r[5] = (short)f2bf(b.y);
  r[6] = (short)f2bf(b.z); r[7] = (short)f2bf(b.w);
  return r;
}

// ---------------------------------------------------------------------------
// transpose + cast f32 [R][C] -> bf16 [C][R]
// ---------------------------------------------------------------------------
__global__ void transpose_cast(const float* __restrict__ src,
                               __hip_bfloat16* __restrict__ dst,
                               int R, int C) {
  __shared__ float t[32][33];
  const int c0 = blockIdx.x * 32, r0 = blockIdx.y * 32;
  const int tx = threadIdx.x, ty = threadIdx.y;  // 32 x 8
#pragma unroll
  for (int i = 0; i < 32; i += 8)
    t[ty + i][tx] = src[(size_t)(r0 + ty + i) * C + c0 + tx];
  __syncthreads();
#pragma unroll
  for (int i = 0; i < 32; i += 8)
    dst[(size_t)(c0 + ty + i) * R + r0 + tx] = __float2bfloat16(t[tx][ty + i]);
}

// ---------------------------------------------------------------------------
// GEMM tile kernel (m97 geometry, BK=64): C = A[128 x KD] * BT-panel^T
// MODE 0: y=z bf16 + per-row partial (sum, sumsq) -> statp[row][4]
// MODE 1: per-row partial sum tanh(z)*wa2 -> scorep[row][4]
// 256 threads, 4 waves (2M x 2N), wave tile 64x64 (fm=4, fn=4), two k-halves
// per step -> 32 MFMA/wave/step. LDS 2x16KB single-buffered.
// Chunk layout: chunk c (0..15) = row-group (c>>1, 16 rows) x k-half (c&1,
// 32 cols); within-chunk lane l holds (row=l&15, kslot=(l>>4)^(l&3)) at
// byte 16*l (linear gload_lds dest, pre-swizzled source; 0 bank conflicts).
// ---------------------------------------------------------------------------
#define BM 128
#define BN 128
#define BK 64

template <int KD, bool AF32, int MODE>
__global__ __launch_bounds__(256, AF32 ? 2 : 3)
void gemm_tile(const void* Ap, const __hip_bfloat16* __restrict__ BT,
               const float* __restrict__ bias,
               __hip_bfloat16* __restrict__ ybuf,
               float2* __restrict__ statp,
               const float* __restrict__ wa2,
               float* __restrict__ scorep) {
  __shared__ __align__(16) char smem[32768];
  __hip_bfloat16* AtP = (__hip_bfloat16*)smem;             // 16 KB (16 chunks)
  __hip_bfloat16* BtP = (__hip_bfloat16*)(smem + 16384);   // 16 KB

  const int tid  = threadIdx.x;     // 256
  const int lane = tid & 63;
  const int w    = tid >> 6;        // 4 waves
  const int wm   = w >> 1;          // 0..1
  const int wn   = w & 1;           // 0..1
  const int l16  = lane & 15;
  const int lg   = lane >> 4;       // 0..3

  // XCD-bijective remap (grid 2048 % 8 == 0)
  const int cpx = gridDim.x >> 3;
  int bid = blockIdx.x;
  bid = (bid & 7) * cpx + (bid >> 3);
  const int n_blk   = bid & 3;
  const int row_blk = bid >> 2;
  const size_t row0 = (size_t)row_blk * BM;
  const int col0    = n_blk * BN;

  // staging geometry (within 1KB chunk)
  const int rS   = lane & 15;                 // row within chunk
  const int sS   = (lane >> 4) ^ (lane & 3);  // source k-slot (pre-swizzle)
  const int dOff = lane * 8;                  // dest elems within chunk
  const int frag_off = l16 * 8 + ((lg ^ (l16 & 3)) << 7);

  constexpr int NT = KD / BK;  // 16 (GEMM1) / 8 (GEMM2,3)
  const __hip_bfloat16* Abf = (const __hip_bfloat16*)Ap;
  const float* Af32 = (const float*)Ap;

  f32x4 acc[4][4];
#pragma unroll
  for (int i = 0; i < 4; i++)
#pragma unroll
    for (int j = 0; j < 4; j++) acc[i][j] = (f32x4){0.f, 0.f, 0.f, 0.f};

  auto stageB = [&](int kb) {
#pragma unroll
    for (int i = 0; i < 4; i++) {
      const int c = w * 4 + i;                      // chunk 0..15
      const int rg = (c >> 1) * 16 + rS;            // BT row (output col)
      const int kc = kb + (c & 1) * 32 + sS * 8;    // k offset
      gload16(BT + (size_t)(col0 + rg) * KD + kc, BtP + c * 512 + dOff);
    }
  };
  auto stageA_g = [&](int kb) {
#pragma unroll
    for (int i = 0; i < 4; i++) {
      const int c = w * 4 + i;
      const int rg = (c >> 1) * 16 + rS;
      const int kc = kb + (c & 1) * 32 + sS * 8;
      gload16(Abf + (row0 + rg) * KD + kc, AtP + c * 512 + dOff);
    }
  };

  // f32 A reg-staging: 2 prefetch sets x 4 chunks x 8 f32 (all static idx)
  float4 ra[2][8];
#define LOADA_(S, KB)                                                          \
  _Pragma("unroll") for (int i = 0; i < 4; i++) {                              \
    const int c_ = w * 4 + i;                                                  \
    const float* gp_ = Af32 + (row0 + (c_ >> 1) * 16 + rS) * KD + (KB) +       \
                       (c_ & 1) * 32 + sS * 8;                                 \
    ra[S][i * 2 + 0] = *(const float4*)gp_;                                    \
    ra[S][i * 2 + 1] = *(const float4*)(gp_ + 4);                              \
  }
#define WRITEA_(S)                                                             \
  _Pragma("unroll") for (int i = 0; i < 4; i++) {                              \
    *reinterpret_cast<bf16x8*>(AtP + (w * 4 + i) * 512 + dOff) =               \
        pack8(ra[S][i * 2 + 0], ra[S][i * 2 + 1]);                             \
  }

#define COMPUTE_STEP                                                           \
  _Pragma("unroll") for (int h = 0; h < 2; h++) {                              \
    bf16x8 af[4], bfr[4];                                                      \
    _Pragma("unroll") for (int fm = 0; fm < 4; fm++)                           \
        af[fm] = *reinterpret_cast<const bf16x8*>(                             \
            AtP + ((wm * 4 + fm) * 2 + h) * 512 + frag_off);                   \
    _Pragma("unroll") for (int fn = 0; fn < 4; fn++)                           \
        bfr[fn] = *reinterpret_cast<const bf16x8*>(                            \
            BtP + ((wn * 4 + fn) * 2 + h) * 512 + frag_off);                   \
    _Pragma("unroll") for (int fm = 0; fm < 4; fm++)                           \
    _Pragma("unroll") for (int fn = 0; fn < 4; fn++)                           \
        acc[fm][fn] = __builtin_amdgcn_mfma_f32_16x16x32_bf16(                 \
            af[fm], bfr[fn], acc[fm][fn], 0, 0, 0);                            \
  }

  if constexpr (AF32) {
    LOADA_(0, 0);
    for (int tb = 0; tb < NT; tb += 2) {
      {  // t = tb: consume set 0, prefetch set 1
        WRITEA_(0);
        stageB(tb * BK);
        __syncthreads();
        if (tb + 1 < NT) { LOADA_(1, (tb + 1) * BK); }
        COMPUTE_STEP
        __syncthreads();
      }
      {  // t = tb+1: consume set 1, prefetch set 0
        WRITEA_(1);
        stageB((tb + 1) * BK);
        __syncthreads();
        if (tb + 2 < NT) { LOADA_(0, (tb + 2) * BK); }
        COMPUTE_STEP
        __syncthreads();
      }
    }
  } else {
    for (int t = 0; t < NT; ++t) {
      stageA_g(t * BK);
      stageB(t * BK);
      __syncthreads();
      COMPUTE_STEP
      __syncthreads();
    }
  }
#undef LOADA_
#undef WRITEA_
#undef COMPUTE_STEP

  // ---------------- epilogue: partial stats / partial scores ----------------
  float* redS = (float*)smem;          // [128][2]
  float* redQ = (float*)smem + 256;    // [128][2]

  float biasv[4];
#pragma unroll
  for (int fn = 0; fn < 4; fn++)
    biasv[fn] = bias[col0 + wn * 64 + fn * 16 + l16];

  if (MODE == 0) {
#pragma unroll
    for (int fm = 0; fm < 4; fm++)
#pragma unroll
      for (int r = 0; r < 4; r++) {
        const int rl = wm * 64 + fm * 16 + lg * 4 + r;
        float s1 = 0.f, s2 = 0.f;
#pragma unroll
        for (int fn = 0; fn < 4; fn++) {
          const float z = acc[fm][fn][r] + biasv[fn];
          s1 += z;
          s2 += z * z;
          ybuf[(row0 + rl) * HDIM + col0 + wn * 64 + fn * 16 + l16] =
              __float2bfloat16(z);
        }
#pragma unroll
        for (int m = 1; m < 16; m <<= 1) {
          s1 += __shfl_xor(s1, m);
          s2 += __shfl_xor(s2, m);
        }
        if (l16 == 0) {
          redS[rl * 2 + wn] = s1;
          redQ[rl * 2 + wn] = s2;
        }
      }
    __syncthreads();
    if (tid < BM) {
      statp[(row0 + tid) * 4 + n_blk] =
          make_float2(redS[tid * 2] + redS[tid * 2 + 1],
                      redQ[tid * 2] + redQ[tid * 2 + 1]);
    }
  } else {
    float wv[4];
#pragma unroll
    for (int fn = 0; fn < 4; fn++)
      wv[fn] = wa2[col0 + wn * 64 + fn * 16 + l16];
#pragma unroll
    for (int fm = 0; fm < 4; fm++)
#pragma unroll
      for (int r = 0; r < 4; r++) {
        const int rl = wm * 64 + fm * 16 + lg * 4 + r;
        float s = 0.f;
#pragma unroll
        for (int fn = 0; fn < 4; fn++) {
          const float z = acc[fm][fn][r] + biasv[fn];
          s += tanhf(z) * wv[fn];
        }
#pragma unroll
        for (int m = 1; m < 16; m <<= 1) s += __shfl_xor(s, m);
        if (l16 == 0) redS[rl * 2 + wn] = s;
      }
    __syncthreads();
    if (tid < BM) {
      scorep[(row0 + tid) * 4 + n_blk] = redS[tid * 2] + redS[tid * 2 + 1];
    }
  }
}

// ---------------------------------------------------------------------------
// ln_apply: h[r][c] = relu((y[r][c] - mu_r) * rs_r * g[c] + be[c]), in-place.
// ---------------------------------------------------------------------------
__global__ __launch_bounds__(256)
void ln_apply(__hip_bfloat16* __restrict__ y,
              const float2* __restrict__ statp,
              const float* __restrict__ g, const float* __restrict__ be) {
  const int row = blockIdx.x * 4 + (threadIdx.x >> 6);
  const int c0 = (threadIdx.x & 63) * 8;
  const float2* sp = statp + (size_t)row * 4;
  float S = 0.f, Q = 0.f;
#pragma unroll
  for (int j = 0; j < 4; j++) {
    const float2 p = sp[j];
    S += p.x;
    Q += p.y;
  }
  const float mu = S * (1.f / 512.f);
  const float var = Q * (1.f / 512.f) - mu * mu;
  const float rs = rsqrtf(var + 1e-5f);

  __hip_bfloat16* yp = y + (size_t)row * HDIM + c0;
  bf16x8 v = *reinterpret_cast<const bf16x8*>(yp);
  const float4 ga = *(const float4*)(g + c0), gb = *(const float4*)(g + c0 + 4);
  const float4 ba = *(const float4*)(be + c0), bb = *(const float4*)(be + c0 + 4);
  float gv[8] = {ga.x, ga.y, ga.z, ga.w, gb.x, gb.y, gb.z, gb.w};
  float bv[8] = {ba.x, ba.y, ba.z, ba.w, bb.x, bb.y, bb.z, bb.w};
  bf16x8 o;
#pragma unroll
  for (int j = 0; j < 8; j++) {
    const float f = bf2f((unsigned short)v[j]);
    const float h = fmaxf((f - mu) * rs * gv[j] + bv[j], 0.f);
    o[j] = (short)f2bf(h);
  }
  *reinterpret_cast<bf16x8*>(yp) = o;
}

// ---------------------------------------------------------------------------
// softmax over 4096 instances per bag; input = 4 partial scores per row + ba2
// ---------------------------------------------------------------------------
__global__ void softmax_bag(const float* __restrict__ scorep,
                            const float* __restrict__ ba2,
                            float* __restrict__ at) {
  const int b = blockIdx.x;
  const int tid = threadIdx.x;  // 256
  const int lane = tid & 63, w = tid >> 6;
  const float bv = ba2[0];
  float v[16];
  float mx = -1e30f;
#pragma unroll
  for (int i = 0; i < 16; i++) {
    const float4 sp = *reinterpret_cast<const float4*>(
        scorep + ((size_t)b * NINST + tid + i * 256) * 4);
    v[i] = sp.x + sp.y + sp.z + sp.w + bv;
    mx = fmaxf(mx, v[i]);
  }
#pragma unroll
  for (int off = 32; off; off >>= 1) mx = fmaxf(mx, __shfl_xor(mx, off));
  __shared__ float red[4];
  if (lane == 0) red[w] = mx;
  __syncthreads();
  mx = fmaxf(fmaxf(red[0], red[1]), fmaxf(red[2], red[3]));
  float sum = 0.f;
#pragma unroll
  for (int i = 0; i < 16; i++) {
    v[i] = expf(v[i] - mx);
    sum += v[i];
  }
#pragma unroll
  for (int off = 32; off; off >>= 1) sum += __shfl_xor(sum, off);
  __shared__ float red2[4];
  if (lane == 0) red2[w] = sum;
  __syncthreads();
  sum = red2[0] + red2[1] + red2[2] + red2[3];
  const float inv = 1.f / sum;
#pragma unroll
  for (int i = 0; i < 16; i++) at[(size_t)b * NINST + tid + i * 256] = v[i] * inv;
}

// ---------------------------------------------------------------------------
// pooled[b,h] = sum_n attn[b,n] * h2[b,n,h]
// ---------------------------------------------------------------------------
__global__ void pooled_partial(const __hip_bfloat16* __restrict__ h2,
                               const float* __restrict__ at,
                               float* __restrict__ part) {
  const int bid = blockIdx.x;
  const int b = bid >> 5, cc = (bid >> 3) & 3, nch = bid & 7;
  const int tid = threadIdx.x;  // 256
  const int c4 = (tid & 31) * 4, sub = tid >> 5;
  const int n0 = nch * 512;
  const size_t base = (size_t)b * NINST;
  float a0 = 0.f, a1 = 0.f, a2 = 0.f, a3 = 0.f;
  for (int n = n0 + sub; n < n0 + 512; n += 8) {
    const float a = at[base + n];
    const ushort4 u = *reinterpret_cast<const ushort4*>(
        &h2[(base + n) * HDIM + cc * 128 + c4]);
    a0 += a * bf2f(u.x);
    a1 += a * bf2f(u.y);
    a2 += a * bf2f(u.z);
    a3 += a * bf2f(u.w);
  }
  __shared__ float pb[8][128];
  pb[sub][c4 + 0] = a0;
  pb[sub][c4 + 1] = a1;
  pb[sub][c4 + 2] = a2;
  pb[sub][c4 + 3] = a3;
  __syncthreads();
  if (tid < 128) {
    float s = 0.f;
#pragma unroll
    for (int j = 0; j < 8; j++) s += pb[j][tid];
    part[(size_t)nch * 8192 + b * 512 + cc * 128 + tid] = s;
  }
}

__global__ void pooled_reduce(const float* __restrict__ part,
                              float* __restrict__ pooled) {
  const int i = blockIdx.x * 256 + threadIdx.x;  // 8192 total
  float s = 0.f;
#pragma unroll
  for (int j = 0; j < 8; j++) s += part[(size_t)j * 8192 + i];
  pooled[i] = s;
}

// ---------------------------------------------------------------------------
// classifier
// ---------------------------------------------------------------------------
__global__ void classifier(const float* __restrict__ pooled,
                           const float* __restrict__ Wc1,
                           const float* __restrict__ bc1,
                           const float* __restrict__ Wc2,
                           const float* __restrict__ bc2,
                           float* __restrict__ out) {
  __shared__ float P[NBAG][512];
  __shared__ float Rb[NBAG][512];
  const int tid = threadIdx.x;  // 512
#pragma unroll
  for (int i = 0; i < NBAG; i++) P[i][tid] = pooled[i * 512 + tid];
  __syncthreads();
  float r[NBAG];
#pragma unroll
  for (int i = 0; i < NBAG; i++) r[i] = 0.f;
  for (int k = 0; k < 512; k++) {
    const float wv = Wc1[k * 512 + tid];
#pragma unroll
    for (int i = 0; i < NBAG; i++) r[i] += P[i][k] * wv;
  }
#pragma unroll
  for (int i = 0; i < NBAG; i++) Rb[i][tid] = fmaxf(r[i] + bc1[tid], 0.f);
  __syncthreads();
  if (tid < 32) {
    const int i = tid >> 1, c = tid & 1;
    float s = bc2[c];
    for (int k = 0; k < 512; k++) s += Rb[i][k] * Wc2[k * 2 + c];
    out[i * 2 + c] = s;
  }
}

// ---------------------------------------------------------------------------
extern "C" void kernel_launch(void* const* d_in, const int* in_sizes, int n_in,
                              void* d_out, int out_size, void* d_ws,
                              size_t ws_size, hipStream_t stream) {
  const float* x   = (const float*)d_in[0];
  const float* W1  = (const float*)d_in[1];
  const float* b1  = (const float*)d_in[2];
  const float* g1  = (const float*)d_in[3];
  const float* be1 = (const float*)d_in[4];
  const float* W2  = (const float*)d_in[5];
  const float* b2  = (const float*)d_in[6];
  const float* g2  = (const float*)d_in[7];
  const float* be2 = (const float*)d_in[8];
  const float* Wa1 = (const float*)d_in[9];
  const float* ba1 = (const float*)d_in[10];
  const float* wa2 = (const float*)d_in[11];
  const float* ba2 = (const float*)d_in[12];
  const float* Wc1 = (const float*)d_in[13];
  const float* bc1 = (const float*)d_in[14];
  const float* Wc2 = (const float*)d_in[15];
  const float* bc2 = (const float*)d_in[16];
  float* out = (float*)d_out;

  char* ws = (char*)d_ws;
  __hip_bfloat16* W1T = (__hip_bfloat16*)(ws + 0);          // 1 MB
  __hip_bfloat16* W2T = (__hip_bfloat16*)(ws + 1048576);    // 512 KB
  __hip_bfloat16* WaT = (__hip_bfloat16*)(ws + 1572864);    // 512 KB
  float2* statp  = (float2*)(ws + 2097152);                 // 2 MB
  float* scorep  = (float*)(ws + 4194304);                  // 1 MB
  float* attn    = (float*)(ws + 5242880);                  // 256 KB
  float* part    = (float*)(ws + 5505024);                  // 256 KB
  float* pooled  = (float*)(ws + 5767168);                  // 32 KB
  __hip_bfloat16* buf1 = (__hip_bfloat16*)(ws + 8388608);   // 64 MB (y1/h1)
  __hip_bfloat16* buf2 = (__hip_bfloat16*)(ws + 75497472);  // 64 MB (y2/h2)

  transpose_cast<<<dim3(16, 32), dim3(32, 8), 0, stream>>>(W1, W1T, DDIM, HDIM);
  transpose_cast<<<dim3(16, 16), dim3(32, 8), 0, stream>>>(W2, W2T, HDIM, HDIM);
  transpose_cast<<<dim3(16, 16), dim3(32, 8), 0, stream>>>(Wa1, WaT, HDIM, HDIM);

  const int grid = (MTOT / BM) * (HDIM / BN);  // 512 * 4 = 2048

  // GEMM1: y1 = x @ W1 + b1 (bf16) + stats
  gemm_tile<DDIM, true, 0><<<grid, 256, 0, stream>>>(
      x, W1T, b1, buf1, statp, nullptr, nullptr);
  ln_apply<<<MTOT / 4, 256, 0, stream>>>(buf1, statp, g1, be1);

  // GEMM2: y2 = h1 @ W2 + b2 (bf16) + stats
  gemm_tile<HDIM, false, 0><<<grid, 256, 0, stream>>>(
      buf1, W2T, b2, buf2, statp, nullptr, nullptr);
  ln_apply<<<MTOT / 4, 256, 0, stream>>>(buf2, statp, g2, be2);

  // GEMM3: partial scores = sum tanh(h2 @ Wa1 + ba1) * wa2
  gemm_tile<HDIM, false, 1><<<grid, 256, 0, stream>>>(
      buf2, WaT, ba1, nullptr, nullptr, wa2, scorep);

  softmax_bag<<<NBAG, 256, 0, stream>>>(scorep, ba2, attn);
  pooled_partial<<<512, 256, 0, stream>>>(buf2, attn, part);
  pooled_reduce<<<32, 256, 0, stream>>>(part, pooled);
  classifier<<<1, 512, 0, stream>>>(pooled, Wc1, bc1, Wc2, bc2, out);
}

// Round 7
// 440.884 us; speedup vs baseline: 4.5337x; 1.0145x over previous
//
#include <hip/hip_runtime.h>
#include <hip/hip_bf16.h>

// ---------------------------------------------------------------------------
// AttentionMIL: x[16,4096,1024] -> Linear+LN+ReLU -> Linear+LN+ReLU ->
//               attention (tanh linear -> scalar -> softmax over N) ->
//               weighted pool -> 2-layer classifier -> logits [16,2]
//
// Round 7: 8-phase counted-vmcnt GEMM (m201 structure) at 256x256, BK=64,
// 8 waves. 4 phases per K-tile; vmcnt(4)/(6) only at phase 2/4 ends (never 0
// in main loop); raw s_barrier + lgkmcnt(0) + sched_barrier(0) + setprio.
// GEMM1 fuses f32->bf16 A-cast into reg-staged pipeline. De-fused LN via
// per-block partial stats (2 col-blocks) + ln_apply.
// ---------------------------------------------------------------------------

#define MTOT   65536
#define DDIM   1024
#define HDIM   512
#define NBAG   16
#define NINST  4096

typedef __attribute__((ext_vector_type(8))) short bf16x8;
typedef __attribute__((ext_vector_type(4))) float f32x4;

__device__ __forceinline__ unsigned short f2bf(float f) {
  __hip_bfloat16 h = __float2bfloat16(f);
  unsigned short u;
  __builtin_memcpy(&u, &h, 2);
  return u;
}
__device__ __forceinline__ float bf2f(unsigned short u) {
  unsigned int x = ((unsigned int)u) << 16;
  float f;
  __builtin_memcpy(&f, &x, 4);
  return f;
}

__device__ __forceinline__ void gload16(const void* g, void* l) {
  __builtin_amdgcn_global_load_lds(
      (const __attribute__((address_space(1))) unsigned int*)g,
      (__attribute__((address_space(3))) unsigned int*)l, 16, 0, 0);
}

__device__ __forceinline__ bf16x8 pack8(float4 a, float4 b) {
  bf16x8 r;
  r[0] = (short)f2bf(a.x); r[1] = (short)f2bf(a.y);
  r[2] = (short)f2bf(a.z); r[3] = (short)f2bf(a.w);
  r[4] = (short)f2bf(b.x); r[5] = (short)f2bf(b.y);
  r[6] = (short)f2bf(b.z); r[7] = (short)f2bf(b.w);
  return r;
}

#define VMW(N) asm volatile("s_waitcnt vmcnt(" #N ")" ::: "memory")
#define LKW0   asm volatile("s_waitcnt lgkmcnt(0)" ::: "memory")
#define SB0    __builtin_amdgcn_sched_barrier(0)
#define BARRIER __builtin_amdgcn_s_barrier()

// ---------------------------------------------------------------------------
// transpose + cast f32 [R][C] -> bf16 [C][R]
// ---------------------------------------------------------------------------
__global__ void transpose_cast(const float* __restrict__ src,
                               __hip_bfloat16* __restrict__ dst,
                               int R, int C) {
  __shared__ float t[32][33];
  const int c0 = blockIdx.x * 32, r0 = blockIdx.y * 32;
  const int tx = threadIdx.x, ty = threadIdx.y;  // 32 x 8
#pragma unroll
  for (int i = 0; i < 32; i += 8)
    t[ty + i][tx] = src[(size_t)(r0 + ty + i) * C + c0 + tx];
  __syncthreads();
#pragma unroll
  for (int i = 0; i < 32; i += 8)
    dst[(size_t)(c0 + ty + i) * R + r0 + tx] = __float2bfloat16(t[tx][ty + i]);
}

// ---------------------------------------------------------------------------
// 8-phase GEMM: C-tile(256x256) = A[256 x KD] * BT-panel(256 rows of W^T)^T
// 512 threads, 8 waves (2M x 4N), per-wave C = 128x64 (8 M-frags x 4 N-frags),
// acc = 128 VGPR. LDS 128KB: A[2 bufs][2 khalf][16 chunks], B same.
// Chunk = 16 rows x 32 k bf16 (1KB); lane l <-> (row l&15, kslot (l>>4)^(l&3))
// at byte 16l: linear gload_lds dest + pre-swizzled source; bank-clean reads.
// Per K-tile phases:
//  P1: ds(A h0 Mlo 4 + B h0 4) | stage A(t+1)h0 | bar | lgkm0 | 16 MFMA | bar
//  P2: ds(A h0 Mhi 4)          | stage B(t+1)h0 | bar | lgkm0 | 16 MFMA | VMW | bar
//  P3: ds(A h1 Mlo 4 + B h1 4) | stage A(t+1)h1 | bar | lgkm0 | 16 MFMA | bar
//  P4: ds(A h1 Mhi 4)          | stage B(t+1)h1 | bar | lgkm0 | 16 MFMA | VMW | bar
// VMW: bf16-A = vmcnt(4); f32-A (4 reg-loads replace 2 gloads per A-half,
// cvt+ds_write 2 phases after issue) = vmcnt(6). In-order vmcnt retire =>
// at P2-end all of {A(t)h1,B(t)h1} landed; at P4-end {A(t+1)h0,B(t+1)h0}.
// MODE 0: z bf16 out + per-row partial (sum,sumsq) -> statp[row][2]
// MODE 1: per-row partial sum tanh(z)*wa2 -> scorep[row][2]
// ---------------------------------------------------------------------------
#define BM 256
#define BN 256
#define BK 64

template <int KD, bool AF32, int MODE>
__global__ __launch_bounds__(512, 2)
void gemm_tile(const void* Ap, const __hip_bfloat16* __restrict__ BT,
               const float* __restrict__ bias,
               __hip_bfloat16* __restrict__ ybuf,
               float2* __restrict__ statp,
               const float* __restrict__ wa2,
               float* __restrict__ scorep) {
  __shared__ __align__(16) char smem[131072];
  // layout (bytes): A buf0 @0, A buf1 @32768, B buf0 @65536, B buf1 @98304
  // within operand buf: khalf*16384 + chunk*1024 + lane*16

  const int tid  = threadIdx.x;     // 512
  const int lane = tid & 63;
  const int w    = tid >> 6;        // 8 waves
  const int wm   = w >> 2;          // 0..1  (M half)
  const int wn   = w & 3;           // 0..3  (N quarter)
  const int l16  = lane & 15;
  const int lg   = lane >> 4;

  const int rS = lane & 15;                  // row within staged chunk
  const int sS = (lane >> 4) ^ (lane & 3);   // pre-swizzled source k-slot
  const int frag_off = l16 * 8 + ((lg ^ (l16 & 3)) << 7);  // elems

  // XCD-bijective remap (grid 512 % 8 == 0): contiguous row panels per XCD
  const int cpx = gridDim.x >> 3;
  int bid = blockIdx.x;
  bid = (bid & 7) * cpx + (bid >> 3);
  const int n_blk = bid & 1;                 // 512 / BN = 2
  const size_t row0 = (size_t)(bid >> 1) * BM;
  const int col0 = n_blk * BN;

  constexpr int NT = KD / BK;  // 16 (GEMM1) / 8 (GEMM2,3)
  const __hip_bfloat16* Abf = (const __hip_bfloat16*)Ap;
  const float* Af32 = (const float*)Ap;

  f32x4 acc[8][4];
#pragma unroll
  for (int i = 0; i < 8; i++)
#pragma unroll
    for (int j = 0; j < 4; j++) acc[i][j] = (f32x4){0.f, 0.f, 0.f, 0.f};

  auto ldsA = [&](int buf, int h) -> __hip_bfloat16* {
    return (__hip_bfloat16*)(smem + buf * 32768 + h * 16384);
  };
  auto ldsB = [&](int buf, int h) -> __hip_bfloat16* {
    return (__hip_bfloat16*)(smem + 65536 + buf * 32768 + h * 16384);
  };

  // wave w stages chunks {w, w+8} of a half-tile (wave-uniform LDS base ✓)
  auto stageB_h = [&](int kb, int buf, int h) {
#pragma unroll
    for (int j = 0; j < 2; j++) {
      const int c = w + j * 8;
      gload16(BT + (size_t)(col0 + c * 16 + rS) * KD + kb + h * 32 + sS * 8,
              ldsB(buf, h) + c * 512 + lane * 8);
    }
  };
  auto stageA_h = [&](int kb, int buf, int h) {  // bf16 A (GEMM2/3)
#pragma unroll
    for (int j = 0; j < 2; j++) {
      const int c = w + j * 8;
      gload16(Abf + (row0 + c * 16 + rS) * KD + kb + h * 32 + sS * 8,
              ldsA(buf, h) + c * 512 + lane * 8);
    }
  };

  // f32 A reg staging (GEMM1): 4 float4 per half-tile per thread
  float4 set0[4], set1[4];
  auto loadF32 = [&](float4* s, int kb, int h) {
#pragma unroll
    for (int j = 0; j < 2; j++) {
      const float* gp =
          Af32 + (row0 + (w + j * 8) * 16 + rS) * KD + kb + h * 32 + sS * 8;
      s[j * 2 + 0] = *(const float4*)gp;
      s[j * 2 + 1] = *(const float4*)(gp + 4);
    }
  };
  auto cvtWrite = [&](const float4* s, int buf, int h) {
#pragma unroll
    for (int j = 0; j < 2; j++)
      *reinterpret_cast<bf16x8*>(ldsA(buf, h) + (w + j * 8) * 512 + lane * 8) =
          pack8(s[j * 2 + 0], s[j * 2 + 1]);
  };

  auto rdA = [&](bf16x8* af, int buf, int h, int mh) {
#pragma unroll
    for (int f = 0; f < 4; f++)
      af[f] = *reinterpret_cast<const bf16x8*>(
          ldsA(buf, h) + (wm * 8 + mh * 4 + f) * 512 + frag_off);
  };
  auto rdB = [&](bf16x8* bf, int buf, int h) {
#pragma unroll
    for (int n = 0; n < 4; n++)
      bf[n] = *reinterpret_cast<const bf16x8*>(
          ldsB(buf, h) + (wn * 4 + n) * 512 + frag_off);
  };
  auto mfma16 = [&](int m0, const bf16x8* af, const bf16x8* bf) {
#pragma unroll
    for (int f = 0; f < 4; f++)
#pragma unroll
      for (int n = 0; n < 4; n++)
        acc[m0 + f][n] = __builtin_amdgcn_mfma_f32_16x16x32_bf16(
            af[f], bf[n], acc[m0 + f][n], 0, 0, 0);
  };

  // ---- prologue: tile 0 ----
  if constexpr (AF32) {
    loadF32(set0, 0, 0);
    stageB_h(0, 0, 0);
    loadF32(set1, 0, 1);
    stageB_h(0, 0, 1);
    cvtWrite(set0, 0, 0);  // compiler auto-waits set0 regs
    VMW(6);                // B(0)h0 landed (set1 + B(0)h1 may pend)
    LKW0;
    BARRIER;
  } else {
    stageA_h(0, 0, 0);
    stageB_h(0, 0, 0);
    stageA_h(0, 0, 1);
    stageB_h(0, 0, 1);
    VMW(4);                // A(0)h0, B(0)h0 landed
    BARRIER;
  }

  // ---- main loop ----
#pragma unroll 2
  for (int t = 0; t < NT; ++t) {
    const int cur = t & 1, nxt = cur ^ 1;
    const bool pf = (t + 1 < NT);
    const int kbn = (t + 1) * BK;
    bf16x8 af[4], bf0[4], bf1[4];

    // ---------- P1 (k-half0, M lo) ----------
    rdA(af, cur, 0, 0);
    rdB(bf0, cur, 0);
    if constexpr (AF32) {
      cvtWrite(set1, cur, 1);          // A(t)h1 arrives mid-tile
      if (pf) loadF32(set0, kbn, 0);   // issue A(t+1)h0
    } else {
      if (pf) stageA_h(kbn, nxt, 0);
    }
    BARRIER;
    LKW0; SB0;
    __builtin_amdgcn_s_setprio(1);
    mfma16(0, af, bf0);
    __builtin_amdgcn_s_setprio(0);
    BARRIER;

    // ---------- P2 (k-half0, M hi) ----------
    rdA(af, cur, 0, 1);
    if (pf) stageB_h(kbn, nxt, 0);
    BARRIER;
    LKW0; SB0;
    __builtin_amdgcn_s_setprio(1);
    mfma16(4, af, bf0);
    __builtin_amdgcn_s_setprio(0);
    if constexpr (AF32) { VMW(6); } else { VMW(4); }  // A(t)h1,B(t)h1 ready
    BARRIER;

    // ---------- P3 (k-half1, M lo) ----------
    rdA(af, cur, 1, 0);
    rdB(bf1, cur, 1);
    if constexpr (AF32) {
      if (pf) {
        cvtWrite(set0, nxt, 0);        // A(t+1)h0 -> LDS
        loadF32(set1, kbn, 1);         // issue A(t+1)h1
      }
    } else {
      if (pf) stageA_h(kbn, nxt, 1);
    }
    BARRIER;
    LKW0; SB0;
    __builtin_amdgcn_s_setprio(1);
    mfma16(0, af, bf1);
    __builtin_amdgcn_s_setprio(0);
    BARRIER;

    // ---------- P4 (k-half1, M hi) ----------
    rdA(af, cur, 1, 1);
    if (pf) stageB_h(kbn, nxt, 1);
    BARRIER;
    LKW0; SB0;
    __builtin_amdgcn_s_setprio(1);
    mfma16(4, af, bf1);
    __builtin_amdgcn_s_setprio(0);
    if constexpr (AF32) { VMW(6); } else { VMW(4); }  // A(t+1)h0,B(t+1)h0 ready
    BARRIER;
  }

  // ---------------- epilogue (redS/redQ alias dead LDS) ----------------
  __syncthreads();
  float* redS = (float*)smem;            // [256][4]
  float* redQ = (float*)(smem + 4096);   // [256][4]

  float biasv[4];
#pragma unroll
  for (int n = 0; n < 4; n++) biasv[n] = bias[col0 + wn * 64 + n * 16 + l16];

  if (MODE == 0) {
#pragma unroll
    for (int f = 0; f < 8; f++)
#pragma unroll
      for (int r = 0; r < 4; r++) {
        const int rl = wm * 128 + f * 16 + lg * 4 + r;
        float s1 = 0.f, s2 = 0.f;
#pragma unroll
        for (int n = 0; n < 4; n++) {
          const float z = acc[f][n][r] + biasv[n];
          s1 += z;
          s2 += z * z;
          ybuf[(row0 + rl) * HDIM + col0 + wn * 64 + n * 16 + l16] =
              __float2bfloat16(z);
        }
#pragma unroll
        for (int m = 1; m < 16; m <<= 1) {
          s1 += __shfl_xor(s1, m);
          s2 += __shfl_xor(s2, m);
        }
        if (l16 == 0) {
          redS[rl * 4 + wn] = s1;
          redQ[rl * 4 + wn] = s2;
        }
      }
    __syncthreads();
    if (tid < BM) {
      const float S = redS[tid * 4] + redS[tid * 4 + 1] + redS[tid * 4 + 2] +
                      redS[tid * 4 + 3];
      const float Q = redQ[tid * 4] + redQ[tid * 4 + 1] + redQ[tid * 4 + 2] +
                      redQ[tid * 4 + 3];
      statp[(row0 + tid) * 2 + n_blk] = make_float2(S, Q);
    }
  } else {
    float wv[4];
#pragma unroll
    for (int n = 0; n < 4; n++) wv[n] = wa2[col0 + wn * 64 + n * 16 + l16];
#pragma unroll
    for (int f = 0; f < 8; f++)
#pragma unroll
      for (int r = 0; r < 4; r++) {
        const int rl = wm * 128 + f * 16 + lg * 4 + r;
        float s = 0.f;
#pragma unroll
        for (int n = 0; n < 4; n++) {
          const float z = acc[f][n][r] + biasv[n];
          s += tanhf(z) * wv[n];
        }
#pragma unroll
        for (int m = 1; m < 16; m <<= 1) s += __shfl_xor(s, m);
        if (l16 == 0) redS[rl * 4 + wn] = s;
      }
    __syncthreads();
    if (tid < BM) {
      scorep[(row0 + tid) * 2 + n_blk] = redS[tid * 4] + redS[tid * 4 + 1] +
                                         redS[tid * 4 + 2] + redS[tid * 4 + 3];
    }
  }
}

// ---------------------------------------------------------------------------
// ln_apply: h[r][c] = relu((y[r][c]-mu)*rs*g[c]+be[c]), in-place; 2 partials.
// ---------------------------------------------------------------------------
__global__ __launch_bounds__(256)
void ln_apply(__hip_bfloat16* __restrict__ y,
              const float2* __restrict__ statp,
              const float* __restrict__ g, const float* __restrict__ be) {
  const int row = blockIdx.x * 4 + (threadIdx.x >> 6);
  const int c0 = (threadIdx.x & 63) * 8;
  const float2 p0 = statp[(size_t)row * 2 + 0];
  const float2 p1 = statp[(size_t)row * 2 + 1];
  const float S = p0.x + p1.x, Q = p0.y + p1.y;
  const float mu = S * (1.f / 512.f);
  const float var = Q * (1.f / 512.f) - mu * mu;
  const float rs = rsqrtf(var + 1e-5f);

  __hip_bfloat16* yp = y + (size_t)row * HDIM + c0;
  bf16x8 v = *reinterpret_cast<const bf16x8*>(yp);
  const float4 ga = *(const float4*)(g + c0), gb = *(const float4*)(g + c0 + 4);
  const float4 ba = *(const float4*)(be + c0), bb = *(const float4*)(be + c0 + 4);
  float gv[8] = {ga.x, ga.y, ga.z, ga.w, gb.x, gb.y, gb.z, gb.w};
  float bv[8] = {ba.x, ba.y, ba.z, ba.w, bb.x, bb.y, bb.z, bb.w};
  bf16x8 o;
#pragma unroll
  for (int j = 0; j < 8; j++) {
    const float f = bf2f((unsigned short)v[j]);
    const float h = fmaxf((f - mu) * rs * gv[j] + bv[j], 0.f);
    o[j] = (short)f2bf(h);
  }
  *reinterpret_cast<bf16x8*>(yp) = o;
}

// ---------------------------------------------------------------------------
// softmax over 4096 instances per bag; input = 2 partial scores per row + ba2
// ---------------------------------------------------------------------------
__global__ void softmax_bag(const float* __restrict__ scorep,
                            const float* __restrict__ ba2,
                            float* __restrict__ at) {
  const int b = blockIdx.x;
  const int tid = threadIdx.x;  // 256
  const int lane = tid & 63, w = tid >> 6;
  const float bv = ba2[0];
  float v[16];
  float mx = -1e30f;
#pragma unroll
  for (int i = 0; i < 16; i++) {
    const float2 sp = *reinterpret_cast<const float2*>(
        scorep + ((size_t)b * NINST + tid + i * 256) * 2);
    v[i] = sp.x + sp.y + bv;
    mx = fmaxf(mx, v[i]);
  }
#pragma unroll
  for (int off = 32; off; off >>= 1) mx = fmaxf(mx, __shfl_xor(mx, off));
  __shared__ float red[4];
  if (lane == 0) red[w] = mx;
  __syncthreads();
  mx = fmaxf(fmaxf(red[0], red[1]), fmaxf(red[2], red[3]));
  float sum = 0.f;
#pragma unroll
  for (int i = 0; i < 16; i++) {
    v[i] = expf(v[i] - mx);
    sum += v[i];
  }
#pragma unroll
  for (int off = 32; off; off >>= 1) sum += __shfl_xor(sum, off);
  __shared__ float red2[4];
  if (lane == 0) red2[w] = sum;
  __syncthreads();
  sum = red2[0] + red2[1] + red2[2] + red2[3];
  const float inv = 1.f / sum;
#pragma unroll
  for (int i = 0; i < 16; i++) at[(size_t)b * NINST + tid + i * 256] = v[i] * inv;
}

// ---------------------------------------------------------------------------
// pooled[b,h] = sum_n attn[b,n] * h2[b,n,h]
// ---------------------------------------------------------------------------
__global__ void pooled_partial(const __hip_bfloat16* __restrict__ h2,
                               const float* __restrict__ at,
                               float* __restrict__ part) {
  const int bid = blockIdx.x;
  const int b = bid >> 5, cc = (bid >> 3) & 3, nch = bid & 7;
  const int tid = threadIdx.x;  // 256
  const int c4 = (tid & 31) * 4, sub = tid >> 5;
  const int n0 = nch * 512;
  const size_t base = (size_t)b * NINST;
  float a0 = 0.f, a1 = 0.f, a2 = 0.f, a3 = 0.f;
  for (int n = n0 + sub; n < n0 + 512; n += 8) {
    const float a = at[base + n];
    const ushort4 u = *reinterpret_cast<const ushort4*>(
        &h2[(base + n) * HDIM + cc * 128 + c4]);
    a0 += a * bf2f(u.x);
    a1 += a * bf2f(u.y);
    a2 += a * bf2f(u.z);
    a3 += a * bf2f(u.w);
  }
  __shared__ float pb[8][128];
  pb[sub][c4 + 0] = a0;
  pb[sub][c4 + 1] = a1;
  pb[sub][c4 + 2] = a2;
  pb[sub][c4 + 3] = a3;
  __syncthreads();
  if (tid < 128) {
    float s = 0.f;
#pragma unroll
    for (int j = 0; j < 8; j++) s += pb[j][tid];
    part[(size_t)nch * 8192 + b * 512 + cc * 128 + tid] = s;
  }
}

__global__ void pooled_reduce(const float* __restrict__ part,
                              float* __restrict__ pooled) {
  const int i = blockIdx.x * 256 + threadIdx.x;  // 8192 total
  float s = 0.f;
#pragma unroll
  for (int j = 0; j < 8; j++) s += part[(size_t)j * 8192 + i];
  pooled[i] = s;
}

// ---------------------------------------------------------------------------
// classifier
// ---------------------------------------------------------------------------
__global__ void classifier(const float* __restrict__ pooled,
                           const float* __restrict__ Wc1,
                           const float* __restrict__ bc1,
                           const float* __restrict__ Wc2,
                           const float* __restrict__ bc2,
                           float* __restrict__ out) {
  __shared__ float P[NBAG][512];
  __shared__ float Rb[NBAG][512];
  const int tid = threadIdx.x;  // 512
#pragma unroll
  for (int i = 0; i < NBAG; i++) P[i][tid] = pooled[i * 512 + tid];
  __syncthreads();
  float r[NBAG];
#pragma unroll
  for (int i = 0; i < NBAG; i++) r[i] = 0.f;
  for (int k = 0; k < 512; k++) {
    const float wv = Wc1[k * 512 + tid];
#pragma unroll
    for (int i = 0; i < NBAG; i++) r[i] += P[i][k] * wv;
  }
#pragma unroll
  for (int i = 0; i < NBAG; i++) Rb[i][tid] = fmaxf(r[i] + bc1[tid], 0.f);
  __syncthreads();
  if (tid < 32) {
    const int i = tid >> 1, c = tid & 1;
    float s = bc2[c];
    for (int k = 0; k < 512; k++) s += Rb[i][k] * Wc2[k * 2 + c];
    out[i * 2 + c] = s;
  }
}

// ---------------------------------------------------------------------------
extern "C" void kernel_launch(void* const* d_in, const int* in_sizes, int n_in,
                              void* d_out, int out_size, void* d_ws,
                              size_t ws_size, hipStream_t stream) {
  const float* x   = (const float*)d_in[0];
  const float* W1  = (const float*)d_in[1];
  const float* b1  = (const float*)d_in[2];
  const float* g1  = (const float*)d_in[3];
  const float* be1 = (const float*)d_in[4];
  const float* W2  = (const float*)d_in[5];
  const float* b2  = (const float*)d_in[6];
  const float* g2  = (const float*)d_in[7];
  const float* be2 = (const float*)d_in[8];
  const float* Wa1 = (const float*)d_in[9];
  const float* ba1 = (const float*)d_in[10];
  const float* wa2 = (const float*)d_in[11];
  const float* ba2 = (const float*)d_in[12];
  const float* Wc1 = (const float*)d_in[13];
  const float* bc1 = (const float*)d_in[14];
  const float* Wc2 = (const float*)d_in[15];
  const float* bc2 = (const float*)d_in[16];
  float* out = (float*)d_out;

  char* ws = (char*)d_ws;
  __hip_bfloat16* W1T = (__hip_bfloat16*)(ws + 0);          // 1 MB
  __hip_bfloat16* W2T = (__hip_bfloat16*)(ws + 1048576);    // 512 KB
  __hip_bfloat16* WaT = (__hip_bfloat16*)(ws + 1572864);    // 512 KB
  float2* statp  = (float2*)(ws + 2097152);                 // 1 MB used
  float* scorep  = (float*)(ws + 4194304);                  // 512 KB used
  float* attn    = (float*)(ws + 5242880);                  // 256 KB
  float* part    = (float*)(ws + 5505024);                  // 256 KB
  float* pooled  = (float*)(ws + 5767168);                  // 32 KB
  __hip_bfloat16* buf1 = (__hip_bfloat16*)(ws + 8388608);   // 64 MB (y1/h1)
  __hip_bfloat16* buf2 = (__hip_bfloat16*)(ws + 75497472);  // 64 MB (y2/h2)

  transpose_cast<<<dim3(16, 32), dim3(32, 8), 0, stream>>>(W1, W1T, DDIM, HDIM);
  transpose_cast<<<dim3(16, 16), dim3(32, 8), 0, stream>>>(W2, W2T, HDIM, HDIM);
  transpose_cast<<<dim3(16, 16), dim3(32, 8), 0, stream>>>(Wa1, WaT, HDIM, HDIM);

  const int grid = (MTOT / BM) * (HDIM / BN);  // 256 * 2 = 512

  // GEMM1: y1 = x @ W1 + b1 (bf16) + stats  (f32 A fused-cast)
  gemm_tile<DDIM, true, 0><<<grid, 512, 0, stream>>>(
      x, W1T, b1, buf1, statp, nullptr, nullptr);
  ln_apply<<<MTOT / 4, 256, 0, stream>>>(buf1, statp, g1, be1);

  // GEMM2: y2 = h1 @ W2 + b2 (bf16) + stats
  gemm_tile<HDIM, false, 0><<<grid, 512, 0, stream>>>(
      buf1, W2T, b2, buf2, statp, nullptr, nullptr);
  ln_apply<<<MTOT / 4, 256, 0, stream>>>(buf2, statp, g2, be2);

  // GEMM3: partial scores = sum tanh(h2 @ Wa1 + ba1) * wa2
  gemm_tile<HDIM, false, 1><<<grid, 512, 0, stream>>>(
      buf2, WaT, ba1, nullptr, nullptr, wa2, scorep);

  softmax_bag<<<NBAG, 256, 0, stream>>>(scorep, ba2, attn);
  pooled_partial<<<512, 256, 0, stream>>>(buf2, attn, part);
  pooled_reduce<<<32, 256, 0, stream>>>(part, pooled);
  classifier<<<1, 512, 0, stream>>>(pooled, Wc1, bc1, Wc2, bc2, out);
}